// Round 9
// baseline (285.085 us; speedup 1.0000x reference)
//
#include <hip/hip_runtime.h>
#include <hip/hip_bf16.h>

typedef __attribute__((ext_vector_type(8))) short short8;
typedef __attribute__((ext_vector_type(4))) float f32x4;

#define WSTRIDE 136  // padded LDS row stride in bf16 elems; 272B/row = 16B-aligned

__device__ __forceinline__ unsigned short f2bf(float x){
    union { float f; unsigned u; } v; v.f = x;
    unsigned r = v.u + 0x7FFFu + ((v.u >> 16) & 1u);   // RNE to bf16
    return (unsigned short)(r >> 16);
}

// stage W (128x128 f32 row-major, W[o][f]) -> LDS bf16 [o][f] with padded stride
__device__ __forceinline__ void stageW(const float* __restrict__ W, unsigned short* Wlds, int tid){
    for (int idx = tid; idx < 2048; idx += 256){
        int row = idx >> 4, ch = idx & 15;
        const f32x4* sp = (const f32x4*)(W + row*128 + ch*8);
        f32x4 p0 = sp[0], p1 = sp[1];
        short8 s;
        s[0]=(short)f2bf(p0[0]); s[1]=(short)f2bf(p0[1]);
        s[2]=(short)f2bf(p0[2]); s[3]=(short)f2bf(p0[3]);
        s[4]=(short)f2bf(p1[0]); s[5]=(short)f2bf(p1[1]);
        s[6]=(short)f2bf(p1[2]); s[7]=(short)f2bf(p1[3]);
        *(short8*)(&Wlds[row*WSTRIDE + ch*8]) = s;
    }
}

// k1: READ-ONLY stats pass, restructured to k3's proven loop shape:
// each lane owns one batch element and loads ALL THREE node rows
// (24 x f32x4 = 1536 B/lane/tile in flight — k3's batch size, which
// sustains ~7 TB/s; the old 8-load chunk shape stalled at 2.5 TB/s).
// Three MFMA accumulator sets give x[bq][v][o] directly (swapped operands:
// D row = feature o, D col = bq); per-node sum/sumsq read off acc[v]+bias.
// x is DISCARDED (k3 recomputes it — cheaper than an HBM round-trip).
__global__ __launch_bounds__(256) void k1_gemm_stats(
    const float* __restrict__ h, const float* __restrict__ W,
    const float* __restrict__ bias, double* __restrict__ partials,
    int Bq, int ntiles, int nBlocks)
{
    __shared__ __align__(16) unsigned short Wlds[128*WSTRIDE];
    __shared__ __align__(16) float biasLds[128];
    __shared__ float wred[4][6];
    int tid = threadIdx.x;
    stageW(W, Wlds, tid);
    if (tid < 128) biasLds[tid] = bias[tid];
    __syncthreads();

    int lane = tid & 63, w = tid >> 6;
    int m = lane & 15, kg = lane >> 4;
    float s0=0.f,s1=0.f,s2=0.f,q0=0.f,q1=0.f,q2=0.f;
    f32x4 zero = {0.f,0.f,0.f,0.f};

    for (int t = blockIdx.x; t < ntiles; t += nBlocks){
        int bq0 = t*64 + w*16;
        int bqv = bq0 + m;
        bool ok = bqv < Bq;
        int bqL = ok ? bqv : (Bq-1);
        const float* hb = h + (long)bqL*384;

        f32x4 acc[3][8];
        #pragma unroll
        for (int v=0;v<3;v++)
            #pragma unroll
            for (int nt=0;nt<8;nt++) acc[v][nt]=zero;

        #pragma unroll
        for (int kc=0;kc<4;kc++){
            int k0 = kc*32 + kg*8;
            f32x4 x0  = *(const f32x4*)(hb + k0);
            f32x4 x0b = *(const f32x4*)(hb + k0 + 4);
            f32x4 x1  = *(const f32x4*)(hb + 128 + k0);
            f32x4 x1b = *(const f32x4*)(hb + 128 + k0 + 4);
            f32x4 x2  = *(const f32x4*)(hb + 256 + k0);
            f32x4 x2b = *(const f32x4*)(hb + 256 + k0 + 4);
            short8 a0, a1, a2;
            #pragma unroll
            for (int i=0;i<4;i++){
                a0[i]   = (short)f2bf(x0[i]);  a0[4+i] = (short)f2bf(x0b[i]);
                a1[i]   = (short)f2bf(x1[i]);  a1[4+i] = (short)f2bf(x1b[i]);
                a2[i]   = (short)f2bf(x2[i]);  a2[4+i] = (short)f2bf(x2b[i]);
            }
            #pragma unroll
            for (int nt=0;nt<8;nt++){
                short8 wf = *(const short8*)(&Wlds[(nt*16+m)*WSTRIDE + k0]);
                acc[0][nt] = __builtin_amdgcn_mfma_f32_16x16x32_bf16(wf, a0, acc[0][nt], 0,0,0);
                acc[1][nt] = __builtin_amdgcn_mfma_f32_16x16x32_bf16(wf, a1, acc[1][nt], 0,0,0);
                acc[2][nt] = __builtin_amdgcn_mfma_f32_16x16x32_bf16(wf, a2, acc[2][nt], 0,0,0);
            }
        }
        // acc[v][nt][j] = x[bqv][node v][o = nt*16 + kg*4 + j] - bias[o]
        float cs0=0.f,cq0=0.f,cs1=0.f,cq1=0.f,cs2=0.f,cq2=0.f;
        #pragma unroll
        for (int nt=0;nt<8;nt++){
            f32x4 bo = *(const f32x4*)(&biasLds[nt*16 + kg*4]);
            #pragma unroll
            for (int j=0;j<4;j++){
                float u0 = acc[0][nt][j] + bo[j];
                float u1 = acc[1][nt][j] + bo[j];
                float u2 = acc[2][nt][j] + bo[j];
                cs0 += u0; cq0 += u0*u0;
                cs1 += u1; cq1 += u1*u1;
                cs2 += u2; cq2 += u2*u2;
            }
        }
        if (ok){
            s0 += cs0; q0 += cq0;
            s1 += cs1; q1 += cq1;
            s2 += cs2; q2 += cq2;
        }
    }

    #pragma unroll
    for (int off=32; off>0; off>>=1){
        s0 += __shfl_down(s0,off,64); s1 += __shfl_down(s1,off,64); s2 += __shfl_down(s2,off,64);
        q0 += __shfl_down(q0,off,64); q1 += __shfl_down(q1,off,64); q2 += __shfl_down(q2,off,64);
    }
    if (lane==0){
        wred[w][0]=s0; wred[w][1]=s1; wred[w][2]=s2;
        wred[w][3]=q0; wred[w][4]=q1; wred[w][5]=q2;
    }
    __syncthreads();
    if (tid < 6){
        double t = (double)wred[0][tid]+(double)wred[1][tid]+(double)wred[2][tid]+(double)wred[3][tid];
        partials[(long)blockIdx.x*6 + tid] = t;
    }
}

// k2: reduce partials, compute mean/rsqrt(var), fold BN+adjacency into 15 coefficients.
__global__ void k_finalize(const double* __restrict__ partials, int nb,
    const float* __restrict__ gamma, const float* __restrict__ beta,
    const int* __restrict__ src, const int* __restrict__ dst, int nE,
    double cnt, float* __restrict__ coef)
{
    __shared__ double red[256];
    __shared__ double tot[6];
    int tid = threadIdx.x;
    double loc[6] = {0,0,0,0,0,0};
    for (int i = tid; i < nb; i += 256){
        #pragma unroll
        for (int c=0;c<6;c++) loc[c] += partials[(long)i*6+c];
    }
    for (int c=0;c<6;c++){
        red[tid] = loc[c];
        __syncthreads();
        for (int s=128;s>0;s>>=1){
            if (tid < s) red[tid] += red[tid+s];
            __syncthreads();
        }
        if (tid==0) tot[c] = red[0];
        __syncthreads();
    }
    if (tid==0){
        float A[9];
        #pragma unroll
        for (int i=0;i<9;i++) A[i]=0.f;
        for (int e=0;e<nE;e++) A[dst[e]*3 + src[e]] += 1.f;
        float meanv[3], rsv[3];
        #pragma unroll
        for (int n=0;n<3;n++){
            double mean = tot[n]/cnt;
            double var  = tot[3+n]/cnt - mean*mean;
            double rs   = 1.0/sqrt(var + 1e-5);
            meanv[n]=(float)mean; rsv[n]=(float)rs;
        }
        #pragma unroll
        for (int v=0;v<3;v++){
            float c_=0.f, rS=0.f;
            #pragma unroll
            for (int u=0;u<3;u++){
                float s_ = A[v*3+u]*gamma[u]*rsv[u];
                coef[v*3+u] = s_;
                rS += s_;
                c_ += A[v*3+u]*(beta[u] - gamma[u]*rsv[u]*meanv[u]);
            }
            coef[9+v]  = c_;   // constant term (BN shift aggregated)
            coef[12+v] = rS;   // bias scale
        }
    }
}

// k3: recompute pass. Each lane owns one batch element (16 bq per wave);
// build the three mixed rows g_v = S[v,:]·h rows once per bq; MFMA with
// A=W-frag so D rows = output features -> packed f32x4 nt-stores.
// Tiles traversed DESCENDING so the h-tail k1 left in L3 is read first.
__global__ __launch_bounds__(256) void k3_recompute(
    const float* __restrict__ h, const float* __restrict__ W,
    const float* __restrict__ bias, const float* __restrict__ coef,
    float* __restrict__ out, int Bq, int ntiles, int nBlocks)
{
    __shared__ __align__(16) unsigned short Wlds[128*WSTRIDE];
    __shared__ __align__(16) float biasLds[128];
    __shared__ float coefLds[15];
    int tid = threadIdx.x;
    stageW(W, Wlds, tid);
    if (tid < 128) biasLds[tid] = bias[tid];
    if (tid < 15)  coefLds[tid] = coef[tid];
    __syncthreads();

    int lane = tid & 63, w = tid >> 6;
    int m = lane & 15, kg = lane >> 4;

    float s00=coefLds[0], s01=coefLds[1], s02=coefLds[2];
    float s10=coefLds[3], s11=coefLds[4], s12=coefLds[5];
    float s20=coefLds[6], s21=coefLds[7], s22=coefLds[8];
    float c0=coefLds[9],  c1=coefLds[10], c2=coefLds[11];
    float r0s=coefLds[12], r1s=coefLds[13], r2s=coefLds[14];
    f32x4 zero = {0.f,0.f,0.f,0.f};

    for (int t = ntiles - 1 - blockIdx.x; t >= 0; t -= nBlocks){
        int bq0 = t*64 + w*16;
        int bqv = bq0 + m;
        bool ok = bqv < Bq;
        int bqL = ok ? bqv : (Bq-1);
        const float* hb = h + (long)bqL*384;

        f32x4 acc[3][8];
        #pragma unroll
        for (int v=0;v<3;v++)
            #pragma unroll
            for (int nt=0;nt<8;nt++) acc[v][nt]=zero;

        #pragma unroll
        for (int kc=0;kc<4;kc++){
            int k0 = kc*32 + kg*8;
            f32x4 x0  = *(const f32x4*)(hb + k0);
            f32x4 x0b = *(const f32x4*)(hb + k0 + 4);
            f32x4 x1  = *(const f32x4*)(hb + 128 + k0);
            f32x4 x1b = *(const f32x4*)(hb + 128 + k0 + 4);
            f32x4 x2  = *(const f32x4*)(hb + 256 + k0);
            f32x4 x2b = *(const f32x4*)(hb + 256 + k0 + 4);
            short8 a0, a1, a2;
            #pragma unroll
            for (int i=0;i<4;i++){
                a0[i]   = (short)f2bf(s00*x0[i]  + s01*x1[i]  + s02*x2[i]);
                a0[4+i] = (short)f2bf(s00*x0b[i] + s01*x1b[i] + s02*x2b[i]);
                a1[i]   = (short)f2bf(s10*x0[i]  + s11*x1[i]  + s12*x2[i]);
                a1[4+i] = (short)f2bf(s10*x0b[i] + s11*x1b[i] + s12*x2b[i]);
                a2[i]   = (short)f2bf(s20*x0[i]  + s21*x1[i]  + s22*x2[i]);
                a2[4+i] = (short)f2bf(s20*x0b[i] + s21*x1b[i] + s22*x2b[i]);
            }
            #pragma unroll
            for (int nt=0;nt<8;nt++){
                short8 wf = *(const short8*)(&Wlds[(nt*16+m)*WSTRIDE + k0]);
                acc[0][nt] = __builtin_amdgcn_mfma_f32_16x16x32_bf16(wf, a0, acc[0][nt], 0,0,0);
                acc[1][nt] = __builtin_amdgcn_mfma_f32_16x16x32_bf16(wf, a1, acc[1][nt], 0,0,0);
                acc[2][nt] = __builtin_amdgcn_mfma_f32_16x16x32_bf16(wf, a2, acc[2][nt], 0,0,0);
            }
        }
        // D layout (swapped operands): row = W row o = nt*16 + kg*4 + j,
        // col = bq-local = m  ->  lane holds 4 consecutive features.
        float* ob = out + (long)bqv*384 + kg*4;
        #pragma unroll
        for (int v=0;v<3;v++){
            float cv = (v==0)?c0:((v==1)?c1:c2);
            float rv = (v==0)?r0s:((v==1)?r1s:r2s);
            #pragma unroll
            for (int nt=0;nt<8;nt++){
                f32x4 bo = *(const f32x4*)(&biasLds[nt*16 + kg*4]);
                f32x4 o4;
                #pragma unroll
                for (int j=0;j<4;j++)
                    o4[j] = fmaxf(acc[v][nt][j] + bo[j]*rv + cv, 0.f);
                if (ok) __builtin_nontemporal_store(o4, (f32x4*)(ob + v*128 + nt*16));
            }
        }
    }
}

extern "C" void kernel_launch(void* const* d_in, const int* in_sizes, int n_in,
                              void* d_out, int out_size, void* d_ws, size_t ws_size,
                              hipStream_t stream) {
    const float* h     = (const float*)d_in[0];
    const float* W     = (const float*)d_in[1];
    const float* bias  = (const float*)d_in[2];
    const float* gamma = (const float*)d_in[3];
    const float* beta  = (const float*)d_in[4];
    const int*   src   = (const int*)d_in[5];
    const int*   dst   = (const int*)d_in[6];
    float* out = (float*)d_out;

    long rows = (long)in_sizes[0] / 128;     // B * 3
    int  Bq   = (int)(rows / 3);
    int nE = in_sizes[5];
    double cnt = (double)Bq * 128.0;
    int ntiles = (Bq + 63) / 64;

    int NB1 = 1024;
    if ((size_t)NB1*48 + 64 > ws_size){
        NB1 = (int)((ws_size > 112 ? (ws_size - 64) : (size_t)48) / 48);
        if (NB1 < 1) NB1 = 1;
        if (NB1 > 1024) NB1 = 1024;
    }
    double* partials = (double*)d_ws;
    float* coef = (float*)((char*)d_ws + (size_t)NB1*48);

    k1_gemm_stats<<<NB1, 256, 0, stream>>>(h, W, bias, partials, Bq, ntiles, NB1);
    k_finalize<<<1, 256, 0, stream>>>(partials, NB1, gamma, beta, src, dst, nE, cnt, coef);
    int NB3 = ntiles < 1024 ? ntiles : 1024;
    k3_recompute<<<NB3, 256, 0, stream>>>(h, W, bias, coef, out, Bq, ntiles, NB3);
}

// Round 10
// 277.087 us; speedup vs baseline: 1.0289x; 1.0289x over previous
//
#include <hip/hip_runtime.h>
#include <hip/hip_bf16.h>

typedef __attribute__((ext_vector_type(8))) short short8;
typedef __attribute__((ext_vector_type(4))) float f32x4;

#define WSTRIDE 136  // padded LDS row stride in bf16 elems; 272B/row = 16B-aligned

__device__ __forceinline__ unsigned short f2bf(float x){
    union { float f; unsigned u; } v; v.f = x;
    unsigned r = v.u + 0x7FFFu + ((v.u >> 16) & 1u);   // RNE to bf16
    return (unsigned short)(r >> 16);
}

// stage W (128x128 f32 row-major, W[o][f]) -> LDS bf16 [o][f] with padded stride
__device__ __forceinline__ void stageW(const float* __restrict__ W, unsigned short* Wlds, int tid){
    for (int idx = tid; idx < 2048; idx += 256){
        int row = idx >> 4, ch = idx & 15;
        const f32x4* sp = (const f32x4*)(W + row*128 + ch*8);
        f32x4 p0 = sp[0], p1 = sp[1];
        short8 s;
        s[0]=(short)f2bf(p0[0]); s[1]=(short)f2bf(p0[1]);
        s[2]=(short)f2bf(p0[2]); s[3]=(short)f2bf(p0[3]);
        s[4]=(short)f2bf(p1[0]); s[5]=(short)f2bf(p1[1]);
        s[6]=(short)f2bf(p1[2]); s[7]=(short)f2bf(p1[3]);
        *(short8*)(&Wlds[row*WSTRIDE + ch*8]) = s;
    }
}

// k1: READ-ONLY stats pass, low-VGPR variant targeting 4 blocks/CU.
// Wave pair structure: pr = w>>1 picks the 16-row group of a 32-row chunk,
// hh = w&1 picks the feature HALF (4 nt tiles instead of 8) -> acc[4] (16
// VGPR) + fbuf[8] (32) + abuf[4] (16) ~= 100 VGPR live set, under the
// 128-VGPR / 4-waves-per-SIMD cliff. The two hh-waves load identical h
// bytes (L1-deduped); HBM traffic unchanged. r7's prefetch pipeline kept:
// issue loads for chunk c+1 -> compute chunk c -> wait+convert c+1.
__global__ __launch_bounds__(256) void k1_gemm_stats(
    const float* __restrict__ h, const float* __restrict__ W,
    const float* __restrict__ bias, double* __restrict__ partials,
    int nChunks, int nBlocks)
{
    __shared__ __align__(16) unsigned short Wlds[128*WSTRIDE];
    __shared__ __align__(16) float biasLds[128];
    __shared__ float wred[4][6];
    int tid = threadIdx.x;
    stageW(W, Wlds, tid);
    if (tid < 128) biasLds[tid] = bias[tid];
    __syncthreads();

    int lane = tid & 63, w = tid >> 6;
    int m = lane & 15, kg = lane >> 4;
    int pr = w >> 1;          // row-group (0/1) within the 32-row chunk
    int hh = w & 1;           // feature half: nt in [hh*4, hh*4+4)
    int ob0 = hh*64;          // output-feature base
    float s0=0.f,s1=0.f,s2=0.f,q0=0.f,q1=0.f,q2=0.f;
    f32x4 zero = {0.f,0.f,0.f,0.f};

    f32x4 fbuf[8];   // raw fp32 prefetch (next chunk)
    short8 abuf[4];  // bf16 operand buffer (current chunk)

    auto issueL = [&](int chunk){
        const float* hrow = h + ((long)(chunk*32 + pr*16 + m))*128;
        #pragma unroll
        for (int kc=0;kc<4;kc++){
            fbuf[kc*2]   = *(const f32x4*)(hrow + kc*32 + kg*8);
            fbuf[kc*2+1] = *(const f32x4*)(hrow + kc*32 + kg*8 + 4);
        }
    };
    auto convert = [&](){
        #pragma unroll
        for (int kc=0;kc<4;kc++){
            f32x4 p0 = fbuf[kc*2], p1 = fbuf[kc*2+1];
            short8 a;
            a[0]=(short)f2bf(p0[0]); a[1]=(short)f2bf(p0[1]);
            a[2]=(short)f2bf(p0[2]); a[3]=(short)f2bf(p0[3]);
            a[4]=(short)f2bf(p1[0]); a[5]=(short)f2bf(p1[1]);
            a[6]=(short)f2bf(p1[2]); a[7]=(short)f2bf(p1[3]);
            abuf[kc] = a;
        }
    };
    auto compute = [&](int chunk){
        int row = chunk*32 + pr*16 + m;
        f32x4 acc[4];
        #pragma unroll
        for (int nt=0;nt<4;nt++) acc[nt]=zero;
        #pragma unroll
        for (int kc=0;kc<4;kc++){
            int k0 = kc*32 + kg*8;
            #pragma unroll
            for (int nt=0;nt<4;nt++){
                short8 wf = *(const short8*)(&Wlds[(ob0+nt*16+m)*WSTRIDE + k0]);
                acc[nt] = __builtin_amdgcn_mfma_f32_16x16x32_bf16(wf, abuf[kc], acc[nt], 0, 0, 0);
            }
        }
        // lane holds x[row][o], o = ob0 + nt*16 + kg*4 + j (all 16 share row)
        float cs = 0.f, cq = 0.f;
        #pragma unroll
        for (int nt=0;nt<4;nt++){
            f32x4 bo = *(const f32x4*)(&biasLds[ob0 + nt*16 + kg*4]);
            float v0 = acc[nt][0] + bo[0];
            float v1 = acc[nt][1] + bo[1];
            float v2 = acc[nt][2] + bo[2];
            float v3 = acc[nt][3] + bo[3];
            cs += (v0+v1)+(v2+v3);
            cq += (v0*v0+v1*v1)+(v2*v2+v3*v3);
        }
        int node = row % 3;
        s0 += (node==0)?cs:0.f; q0 += (node==0)?cq:0.f;
        s1 += (node==1)?cs:0.f; q1 += (node==1)?cq:0.f;
        s2 += (node==2)?cs:0.f; q2 += (node==2)?cq:0.f;
    };

    int c = blockIdx.x;
    bool have = (c < nChunks);
    if (have){ issueL(c); convert(); }
    while (have){
        int cn = c + nBlocks;
        bool haveN = (cn < nChunks);
        if (haveN) issueL(cn);       // in flight across compute
        compute(c);                  // MFMA + stats from abuf only
        if (haveN) convert();        // first use of fbuf -> waits here
        c = cn; have = haveN;
    }

    #pragma unroll
    for (int off=32; off>0; off>>=1){
        s0 += __shfl_down(s0,off,64); s1 += __shfl_down(s1,off,64); s2 += __shfl_down(s2,off,64);
        q0 += __shfl_down(q0,off,64); q1 += __shfl_down(q1,off,64); q2 += __shfl_down(q2,off,64);
    }
    if (lane==0){
        wred[w][0]=s0; wred[w][1]=s1; wred[w][2]=s2;
        wred[w][3]=q0; wred[w][4]=q1; wred[w][5]=q2;
    }
    __syncthreads();
    if (tid < 6){
        double t = (double)wred[0][tid]+(double)wred[1][tid]+(double)wred[2][tid]+(double)wred[3][tid];
        partials[(long)blockIdx.x*6 + tid] = t;
    }
}

// k2: reduce partials, compute mean/rsqrt(var), fold BN+adjacency into 15 coefficients.
__global__ void k_finalize(const double* __restrict__ partials, int nb,
    const float* __restrict__ gamma, const float* __restrict__ beta,
    const int* __restrict__ src, const int* __restrict__ dst, int nE,
    double cnt, float* __restrict__ coef)
{
    __shared__ double red[256];
    __shared__ double tot[6];
    int tid = threadIdx.x;
    double loc[6] = {0,0,0,0,0,0};
    for (int i = tid; i < nb; i += 256){
        #pragma unroll
        for (int c=0;c<6;c++) loc[c] += partials[(long)i*6+c];
    }
    for (int c=0;c<6;c++){
        red[tid] = loc[c];
        __syncthreads();
        for (int s=128;s>0;s>>=1){
            if (tid < s) red[tid] += red[tid+s];
            __syncthreads();
        }
        if (tid==0) tot[c] = red[0];
        __syncthreads();
    }
    if (tid==0){
        float A[9];
        #pragma unroll
        for (int i=0;i<9;i++) A[i]=0.f;
        for (int e=0;e<nE;e++) A[dst[e]*3 + src[e]] += 1.f;
        float meanv[3], rsv[3];
        #pragma unroll
        for (int n=0;n<3;n++){
            double mean = tot[n]/cnt;
            double var  = tot[3+n]/cnt - mean*mean;
            double rs   = 1.0/sqrt(var + 1e-5);
            meanv[n]=(float)mean; rsv[n]=(float)rs;
        }
        #pragma unroll
        for (int v=0;v<3;v++){
            float c_=0.f, rS=0.f;
            #pragma unroll
            for (int u=0;u<3;u++){
                float s_ = A[v*3+u]*gamma[u]*rsv[u];
                coef[v*3+u] = s_;
                rS += s_;
                c_ += A[v*3+u]*(beta[u] - gamma[u]*rsv[u]*meanv[u]);
            }
            coef[9+v]  = c_;   // constant term (BN shift aggregated)
            coef[12+v] = rS;   // bias scale
        }
    }
}

// k3: recompute pass (unchanged from round 7 — best known). Each lane owns
// one batch element; build mixed rows g_v = S[v,:]·h once per bq; MFMA with
// A=W-frag so D rows = output features -> packed f32x4 nt-stores.
// Tiles traversed DESCENDING so the h-tail k1 left in L3 is read first.
__global__ __launch_bounds__(256) void k3_recompute(
    const float* __restrict__ h, const float* __restrict__ W,
    const float* __restrict__ bias, const float* __restrict__ coef,
    float* __restrict__ out, int Bq, int ntiles, int nBlocks)
{
    __shared__ __align__(16) unsigned short Wlds[128*WSTRIDE];
    __shared__ __align__(16) float biasLds[128];
    __shared__ float coefLds[15];
    int tid = threadIdx.x;
    stageW(W, Wlds, tid);
    if (tid < 128) biasLds[tid] = bias[tid];
    if (tid < 15)  coefLds[tid] = coef[tid];
    __syncthreads();

    int lane = tid & 63, w = tid >> 6;
    int m = lane & 15, kg = lane >> 4;

    float s00=coefLds[0], s01=coefLds[1], s02=coefLds[2];
    float s10=coefLds[3], s11=coefLds[4], s12=coefLds[5];
    float s20=coefLds[6], s21=coefLds[7], s22=coefLds[8];
    float c0=coefLds[9],  c1=coefLds[10], c2=coefLds[11];
    float r0s=coefLds[12], r1s=coefLds[13], r2s=coefLds[14];
    f32x4 zero = {0.f,0.f,0.f,0.f};

    for (int t = ntiles - 1 - blockIdx.x; t >= 0; t -= nBlocks){
        int bq0 = t*64 + w*16;
        int bqv = bq0 + m;
        bool ok = bqv < Bq;
        int bqL = ok ? bqv : (Bq-1);
        const float* hb = h + (long)bqL*384;

        f32x4 acc[3][8];
        #pragma unroll
        for (int v=0;v<3;v++)
            #pragma unroll
            for (int nt=0;nt<8;nt++) acc[v][nt]=zero;

        #pragma unroll
        for (int kc=0;kc<4;kc++){
            int k0 = kc*32 + kg*8;
            f32x4 x0  = *(const f32x4*)(hb + k0);
            f32x4 x0b = *(const f32x4*)(hb + k0 + 4);
            f32x4 x1  = *(const f32x4*)(hb + 128 + k0);
            f32x4 x1b = *(const f32x4*)(hb + 128 + k0 + 4);
            f32x4 x2  = *(const f32x4*)(hb + 256 + k0);
            f32x4 x2b = *(const f32x4*)(hb + 256 + k0 + 4);
            short8 a0, a1, a2;
            #pragma unroll
            for (int i=0;i<4;i++){
                a0[i]   = (short)f2bf(s00*x0[i]  + s01*x1[i]  + s02*x2[i]);
                a0[4+i] = (short)f2bf(s00*x0b[i] + s01*x1b[i] + s02*x2b[i]);
                a1[i]   = (short)f2bf(s10*x0[i]  + s11*x1[i]  + s12*x2[i]);
                a1[4+i] = (short)f2bf(s10*x0b[i] + s11*x1b[i] + s12*x2b[i]);
                a2[i]   = (short)f2bf(s20*x0[i]  + s21*x1[i]  + s22*x2[i]);
                a2[4+i] = (short)f2bf(s20*x0b[i] + s21*x1b[i] + s22*x2b[i]);
            }
            #pragma unroll
            for (int nt=0;nt<8;nt++){
                short8 wf = *(const short8*)(&Wlds[(nt*16+m)*WSTRIDE + k0]);
                acc[0][nt] = __builtin_amdgcn_mfma_f32_16x16x32_bf16(wf, a0, acc[0][nt], 0,0,0);
                acc[1][nt] = __builtin_amdgcn_mfma_f32_16x16x32_bf16(wf, a1, acc[1][nt], 0,0,0);
                acc[2][nt] = __builtin_amdgcn_mfma_f32_16x16x32_bf16(wf, a2, acc[2][nt], 0,0,0);
            }
        }
        // D layout (swapped operands): row = W row o = nt*16 + kg*4 + j,
        // col = bq-local = m  ->  lane holds 4 consecutive features.
        float* ob = out + (long)bqv*384 + kg*4;
        #pragma unroll
        for (int v=0;v<3;v++){
            float cv = (v==0)?c0:((v==1)?c1:c2);
            float rv = (v==0)?r0s:((v==1)?r1s:r2s);
            #pragma unroll
            for (int nt=0;nt<8;nt++){
                f32x4 bo = *(const f32x4*)(&biasLds[nt*16 + kg*4]);
                f32x4 o4;
                #pragma unroll
                for (int j=0;j<4;j++)
                    o4[j] = fmaxf(acc[v][nt][j] + bo[j]*rv + cv, 0.f);
                if (ok) __builtin_nontemporal_store(o4, (f32x4*)(ob + v*128 + nt*16));
            }
        }
    }
}

extern "C" void kernel_launch(void* const* d_in, const int* in_sizes, int n_in,
                              void* d_out, int out_size, void* d_ws, size_t ws_size,
                              hipStream_t stream) {
    const float* h     = (const float*)d_in[0];
    const float* W     = (const float*)d_in[1];
    const float* bias  = (const float*)d_in[2];
    const float* gamma = (const float*)d_in[3];
    const float* beta  = (const float*)d_in[4];
    const int*   src   = (const int*)d_in[5];
    const int*   dst   = (const int*)d_in[6];
    float* out = (float*)d_out;

    long rows = (long)in_sizes[0] / 128;     // B * 3
    int  Bq   = (int)(rows / 3);
    int nE = in_sizes[5];
    double cnt = (double)Bq * 128.0;

    int nChunks = (int)(rows / 32);          // 32-row chunks for low-VGPR k1
    int NB1 = 1024;
    if ((size_t)NB1*48 + 64 > ws_size){
        NB1 = (int)((ws_size > 112 ? (ws_size - 64) : (size_t)48) / 48);
        if (NB1 < 1) NB1 = 1;
        if (NB1 > 1024) NB1 = 1024;
    }
    double* partials = (double*)d_ws;
    float* coef = (float*)((char*)d_ws + (size_t)NB1*48);

    k1_gemm_stats<<<NB1, 256, 0, stream>>>(h, W, bias, partials, nChunks, NB1);
    k_finalize<<<1, 256, 0, stream>>>(partials, NB1, gamma, beta, src, dst, nE, cnt, coef);
    int ntiles = (Bq + 63) / 64;
    int NB3 = ntiles < 1024 ? ntiles : 1024;
    k3_recompute<<<NB3, 256, 0, stream>>>(h, W, bias, coef, out, Bq, ntiles, NB3);
}

// Round 11
// 246.748 us; speedup vs baseline: 1.1554x; 1.1230x over previous
//
#include <hip/hip_runtime.h>
#include <hip/hip_bf16.h>

typedef __attribute__((ext_vector_type(8))) short short8;
typedef __attribute__((ext_vector_type(4))) float f32x4;

#define WSTRIDE 136  // padded LDS row stride in bf16 elems; 272B/row = 16B-aligned

__device__ __forceinline__ unsigned short f2bf(float x){
    union { float f; unsigned u; } v; v.f = x;
    unsigned r = v.u + 0x7FFFu + ((v.u >> 16) & 1u);   // RNE to bf16
    return (unsigned short)(r >> 16);
}

// stage W (128x128 f32 row-major, W[o][f]) -> LDS bf16 [o][f] with padded stride
__device__ __forceinline__ void stageW(const float* __restrict__ W, unsigned short* Wlds, int tid){
    for (int idx = tid; idx < 2048; idx += 256){
        int row = idx >> 4, ch = idx & 15;
        const f32x4* sp = (const f32x4*)(W + row*128 + ch*8);
        f32x4 p0 = sp[0], p1 = sp[1];
        short8 s;
        s[0]=(short)f2bf(p0[0]); s[1]=(short)f2bf(p0[1]);
        s[2]=(short)f2bf(p0[2]); s[3]=(short)f2bf(p0[3]);
        s[4]=(short)f2bf(p1[0]); s[5]=(short)f2bf(p1[1]);
        s[6]=(short)f2bf(p1[2]); s[7]=(short)f2bf(p1[3]);
        *(short8*)(&Wlds[row*WSTRIDE + ch*8]) = s;
    }
}

// k1: READ-ONLY stats pass (r7 structure) + sched_barrier fences.
// Theory: hipcc's scheduler was sinking the prefetch loads down to their
// first use (shortening fbuf's 32-VGPR live range), collapsing every
// source-level pipeline variant (r4/r6/r7/r8/r10 all ~150us) to the same
// zero-distance schedule. sched_barrier(0) after issueL pins the loads
// ABOVE the compute section; one after compute keeps convert's vmcnt
// waits BELOW the MFMA section. No other change vs r7.
__global__ __launch_bounds__(256) void k1_gemm_stats(
    const float* __restrict__ h, const float* __restrict__ W,
    const float* __restrict__ bias, double* __restrict__ partials,
    int nChunks, int nBlocks)
{
    __shared__ __align__(16) unsigned short Wlds[128*WSTRIDE];
    __shared__ __align__(16) float biasLds[128];
    __shared__ float wred[4][6];
    int tid = threadIdx.x;
    stageW(W, Wlds, tid);
    if (tid < 128) biasLds[tid] = bias[tid];
    __syncthreads();

    int lane = tid & 63, w = tid >> 6;
    int m = lane & 15, kg = lane >> 4;
    float s0=0.f,s1=0.f,s2=0.f,q0=0.f,q1=0.f,q2=0.f;
    f32x4 zero = {0.f,0.f,0.f,0.f};

    f32x4 fbuf[8];   // raw fp32 prefetch (next chunk)
    short8 abuf[4];  // bf16 operand buffer (current chunk)

    auto issueL = [&](int chunk){
        const float* hrow = h + ((long)(chunk*64 + w*16 + m))*128;
        #pragma unroll
        for (int kc=0;kc<4;kc++){
            fbuf[kc*2]   = *(const f32x4*)(hrow + kc*32 + kg*8);
            fbuf[kc*2+1] = *(const f32x4*)(hrow + kc*32 + kg*8 + 4);
        }
    };
    auto convert = [&](){
        #pragma unroll
        for (int kc=0;kc<4;kc++){
            f32x4 p0 = fbuf[kc*2], p1 = fbuf[kc*2+1];
            short8 a;
            a[0]=(short)f2bf(p0[0]); a[1]=(short)f2bf(p0[1]);
            a[2]=(short)f2bf(p0[2]); a[3]=(short)f2bf(p0[3]);
            a[4]=(short)f2bf(p1[0]); a[5]=(short)f2bf(p1[1]);
            a[6]=(short)f2bf(p1[2]); a[7]=(short)f2bf(p1[3]);
            abuf[kc] = a;
        }
    };
    auto compute = [&](int chunk){
        int row = chunk*64 + w*16 + m;
        f32x4 acc[8];
        #pragma unroll
        for (int nt=0;nt<8;nt++) acc[nt]=zero;
        #pragma unroll
        for (int kc=0;kc<4;kc++){
            int k0 = kc*32 + kg*8;
            #pragma unroll
            for (int nt=0;nt<8;nt++){
                short8 wf = *(const short8*)(&Wlds[(nt*16+m)*WSTRIDE + k0]);
                acc[nt] = __builtin_amdgcn_mfma_f32_16x16x32_bf16(wf, abuf[kc], acc[nt], 0, 0, 0);
            }
        }
        float cs = 0.f, cq = 0.f;
        #pragma unroll
        for (int nt=0;nt<8;nt++){
            f32x4 bo = *(const f32x4*)(&biasLds[nt*16 + kg*4]);
            float v0 = acc[nt][0] + bo[0];
            float v1 = acc[nt][1] + bo[1];
            float v2 = acc[nt][2] + bo[2];
            float v3 = acc[nt][3] + bo[3];
            cs += (v0+v1)+(v2+v3);
            cq += (v0*v0+v1*v1)+(v2*v2+v3*v3);
        }
        int node = row % 3;
        s0 += (node==0)?cs:0.f; q0 += (node==0)?cq:0.f;
        s1 += (node==1)?cs:0.f; q1 += (node==1)?cq:0.f;
        s2 += (node==2)?cs:0.f; q2 += (node==2)?cq:0.f;
    };

    int c = blockIdx.x;
    bool have = (c < nChunks);
    if (have){ issueL(c); convert(); }
    while (have){
        int cn = c + nBlocks;
        bool haveN = (cn < nChunks);
        if (haveN) issueL(cn);                    // loads issued here...
        __builtin_amdgcn_sched_barrier(0);        // ...and PINNED here
        compute(c);                               // MFMA + stats from abuf
        __builtin_amdgcn_sched_barrier(0);        // waits can't float up
        if (haveN) convert();                     // first fbuf use -> vmcnt
        c = cn; have = haveN;
    }

    #pragma unroll
    for (int off=32; off>0; off>>=1){
        s0 += __shfl_down(s0,off,64); s1 += __shfl_down(s1,off,64); s2 += __shfl_down(s2,off,64);
        q0 += __shfl_down(q0,off,64); q1 += __shfl_down(q1,off,64); q2 += __shfl_down(q2,off,64);
    }
    if (lane==0){
        wred[w][0]=s0; wred[w][1]=s1; wred[w][2]=s2;
        wred[w][3]=q0; wred[w][4]=q1; wred[w][5]=q2;
    }
    __syncthreads();
    if (tid < 6){
        double t = (double)wred[0][tid]+(double)wred[1][tid]+(double)wred[2][tid]+(double)wred[3][tid];
        partials[(long)blockIdx.x*6 + tid] = t;
    }
}

// k2: reduce partials, compute mean/rsqrt(var), fold BN+adjacency into 15 coefficients.
__global__ void k_finalize(const double* __restrict__ partials, int nb,
    const float* __restrict__ gamma, const float* __restrict__ beta,
    const int* __restrict__ src, const int* __restrict__ dst, int nE,
    double cnt, float* __restrict__ coef)
{
    __shared__ double red[256];
    __shared__ double tot[6];
    int tid = threadIdx.x;
    double loc[6] = {0,0,0,0,0,0};
    for (int i = tid; i < nb; i += 256){
        #pragma unroll
        for (int c=0;c<6;c++) loc[c] += partials[(long)i*6+c];
    }
    for (int c=0;c<6;c++){
        red[tid] = loc[c];
        __syncthreads();
        for (int s=128;s>0;s>>=1){
            if (tid < s) red[tid] += red[tid+s];
            __syncthreads();
        }
        if (tid==0) tot[c] = red[0];
        __syncthreads();
    }
    if (tid==0){
        float A[9];
        #pragma unroll
        for (int i=0;i<9;i++) A[i]=0.f;
        for (int e=0;e<nE;e++) A[dst[e]*3 + src[e]] += 1.f;
        float meanv[3], rsv[3];
        #pragma unroll
        for (int n=0;n<3;n++){
            double mean = tot[n]/cnt;
            double var  = tot[3+n]/cnt - mean*mean;
            double rs   = 1.0/sqrt(var + 1e-5);
            meanv[n]=(float)mean; rsv[n]=(float)rs;
        }
        #pragma unroll
        for (int v=0;v<3;v++){
            float c_=0.f, rS=0.f;
            #pragma unroll
            for (int u=0;u<3;u++){
                float s_ = A[v*3+u]*gamma[u]*rsv[u];
                coef[v*3+u] = s_;
                rS += s_;
                c_ += A[v*3+u]*(beta[u] - gamma[u]*rsv[u]*meanv[u]);
            }
            coef[9+v]  = c_;   // constant term (BN shift aggregated)
            coef[12+v] = rS;   // bias scale
        }
    }
}

// k3: recompute pass (unchanged from round 7 — best known). Each lane owns
// one batch element; build mixed rows g_v = S[v,:]·h once per bq; MFMA with
// A=W-frag so D rows = output features -> packed f32x4 nt-stores.
// Tiles traversed DESCENDING so the h-tail k1 left in L3 is read first.
__global__ __launch_bounds__(256) void k3_recompute(
    const float* __restrict__ h, const float* __restrict__ W,
    const float* __restrict__ bias, const float* __restrict__ coef,
    float* __restrict__ out, int Bq, int ntiles, int nBlocks)
{
    __shared__ __align__(16) unsigned short Wlds[128*WSTRIDE];
    __shared__ __align__(16) float biasLds[128];
    __shared__ float coefLds[15];
    int tid = threadIdx.x;
    stageW(W, Wlds, tid);
    if (tid < 128) biasLds[tid] = bias[tid];
    if (tid < 15)  coefLds[tid] = coef[tid];
    __syncthreads();

    int lane = tid & 63, w = tid >> 6;
    int m = lane & 15, kg = lane >> 4;

    float s00=coefLds[0], s01=coefLds[1], s02=coefLds[2];
    float s10=coefLds[3], s11=coefLds[4], s12=coefLds[5];
    float s20=coefLds[6], s21=coefLds[7], s22=coefLds[8];
    float c0=coefLds[9],  c1=coefLds[10], c2=coefLds[11];
    float r0s=coefLds[12], r1s=coefLds[13], r2s=coefLds[14];
    f32x4 zero = {0.f,0.f,0.f,0.f};

    for (int t = ntiles - 1 - blockIdx.x; t >= 0; t -= nBlocks){
        int bq0 = t*64 + w*16;
        int bqv = bq0 + m;
        bool ok = bqv < Bq;
        int bqL = ok ? bqv : (Bq-1);
        const float* hb = h + (long)bqL*384;

        f32x4 acc[3][8];
        #pragma unroll
        for (int v=0;v<3;v++)
            #pragma unroll
            for (int nt=0;nt<8;nt++) acc[v][nt]=zero;

        #pragma unroll
        for (int kc=0;kc<4;kc++){
            int k0 = kc*32 + kg*8;
            f32x4 x0  = *(const f32x4*)(hb + k0);
            f32x4 x0b = *(const f32x4*)(hb + k0 + 4);
            f32x4 x1  = *(const f32x4*)(hb + 128 + k0);
            f32x4 x1b = *(const f32x4*)(hb + 128 + k0 + 4);
            f32x4 x2  = *(const f32x4*)(hb + 256 + k0);
            f32x4 x2b = *(const f32x4*)(hb + 256 + k0 + 4);
            short8 a0, a1, a2;
            #pragma unroll
            for (int i=0;i<4;i++){
                a0[i]   = (short)f2bf(s00*x0[i]  + s01*x1[i]  + s02*x2[i]);
                a0[4+i] = (short)f2bf(s00*x0b[i] + s01*x1b[i] + s02*x2b[i]);
                a1[i]   = (short)f2bf(s10*x0[i]  + s11*x1[i]  + s12*x2[i]);
                a1[4+i] = (short)f2bf(s10*x0b[i] + s11*x1b[i] + s12*x2b[i]);
                a2[i]   = (short)f2bf(s20*x0[i]  + s21*x1[i]  + s22*x2[i]);
                a2[4+i] = (short)f2bf(s20*x0b[i] + s21*x1b[i] + s22*x2b[i]);
            }
            #pragma unroll
            for (int nt=0;nt<8;nt++){
                short8 wf = *(const short8*)(&Wlds[(nt*16+m)*WSTRIDE + k0]);
                acc[0][nt] = __builtin_amdgcn_mfma_f32_16x16x32_bf16(wf, a0, acc[0][nt], 0,0,0);
                acc[1][nt] = __builtin_amdgcn_mfma_f32_16x16x32_bf16(wf, a1, acc[1][nt], 0,0,0);
                acc[2][nt] = __builtin_amdgcn_mfma_f32_16x16x32_bf16(wf, a2, acc[2][nt], 0,0,0);
            }
        }
        // D layout (swapped operands): row = W row o = nt*16 + kg*4 + j,
        // col = bq-local = m  ->  lane holds 4 consecutive features.
        float* ob = out + (long)bqv*384 + kg*4;
        #pragma unroll
        for (int v=0;v<3;v++){
            float cv = (v==0)?c0:((v==1)?c1:c2);
            float rv = (v==0)?r0s:((v==1)?r1s:r2s);
            #pragma unroll
            for (int nt=0;nt<8;nt++){
                f32x4 bo = *(const f32x4*)(&biasLds[nt*16 + kg*4]);
                f32x4 o4;
                #pragma unroll
                for (int j=0;j<4;j++)
                    o4[j] = fmaxf(acc[v][nt][j] + bo[j]*rv + cv, 0.f);
                if (ok) __builtin_nontemporal_store(o4, (f32x4*)(ob + v*128 + nt*16));
            }
        }
    }
}

extern "C" void kernel_launch(void* const* d_in, const int* in_sizes, int n_in,
                              void* d_out, int out_size, void* d_ws, size_t ws_size,
                              hipStream_t stream) {
    const float* h     = (const float*)d_in[0];
    const float* W     = (const float*)d_in[1];
    const float* bias  = (const float*)d_in[2];
    const float* gamma = (const float*)d_in[3];
    const float* beta  = (const float*)d_in[4];
    const int*   src   = (const int*)d_in[5];
    const int*   dst   = (const int*)d_in[6];
    float* out = (float*)d_out;

    long rows = (long)in_sizes[0] / 128;     // B * 3
    int  Bq   = (int)(rows / 3);
    int nChunks = (int)(rows / 64);
    int nE = in_sizes[5];
    double cnt = (double)Bq * 128.0;

    // grid 768: co-resident at 3 blocks/CU, zero straggler tail (16 chunks/blk)
    int NB1 = 768;
    if ((size_t)NB1*48 + 64 > ws_size){
        NB1 = (int)((ws_size > 112 ? (ws_size - 64) : (size_t)48) / 48);
        if (NB1 < 1) NB1 = 1;
        if (NB1 > 768) NB1 = 768;
    }
    double* partials = (double*)d_ws;
    float* coef = (float*)((char*)d_ws + (size_t)NB1*48);

    k1_gemm_stats<<<NB1, 256, 0, stream>>>(h, W, bias, partials, nChunks, NB1);
    k_finalize<<<1, 256, 0, stream>>>(partials, NB1, gamma, beta, src, dst, nE, cnt, coef);
    int ntiles = (Bq + 63) / 64;
    int NB3 = ntiles < 768 ? ntiles : 768;
    k3_recompute<<<NB3, 256, 0, stream>>>(h, W, bias, coef, out, Bq, ntiles, NB3);
}